// Round 1
// 276.528 us; speedup vs baseline: 1.0262x; 1.0262x over previous
//
#include <hip/hip_runtime.h>

#define N_NODES 50000
#define N_EDGES 800000
#define D_IN    512
#define D_OUT   128
#define N_SUP   2
#define N_COLS  (N_SUP * D_OUT)            // 256 combined output cols
#define BINS    (N_SUP * N_NODES)
#define NB_S    196                        // coarse buckets per support (256 rows each)
#define NB      (N_SUP * NB_S)             // 392 buckets
#define CAP     4608                       // fixed bucket capacity (mean 4082 + 8 sigma)
#define CHUNK   4096                       // edges per block in coarse pass
#define NCHUNK  ((N_EDGES + CHUNK - 1) / CHUNK)   // 196 blocks per support

typedef __attribute__((ext_vector_type(8))) __bf16 bf16x8;
typedef __attribute__((ext_vector_type(4))) float  f32x4;

// ---------------------------------------------------------------------------
// W convert: kernels [2][512][128] fp32 -> wt2 bf16 in GEMM staging order.
// Also zeroes gcursor (folds away the hipMemsetAsync dispatch).
// ---------------------------------------------------------------------------
__global__ __launch_bounds__(256) void convert_w(const float* __restrict__ w,
                                                 __bf16* __restrict__ wt2,
                                                 int* __restrict__ gcursor) {
    const int g = blockIdx.x * 256 + threadIdx.x;     // 16384 chunks
    if (g < NB) gcursor[g] = 0;
    if (g >= (D_IN / 8) * N_COLS) return;
    const int kq = g >> 8;
    const int n  = g & 255;
    const int s  = n >> 7;
    const int np = n & 127;
    bf16x8 v;
#pragma unroll
    for (int j = 0; j < 8; ++j) {
        const int k = kq * 8 + j;
        v[j] = (__bf16)w[((size_t)s * D_IN + k) * D_OUT + np];
    }
    *(bf16x8*)(wt2 + (size_t)g * 8) = v;
}

// ---------------------------------------------------------------------------
// bf16 MFMA GEMM: pre[s] = bf16(x) @ bf16(W[s]), output bf16. (unchanged)
// ---------------------------------------------------------------------------
__global__ __launch_bounds__(256) void gemm_bf16(const float* __restrict__ x,
                                                 const __bf16* __restrict__ wt2,
                                                 __bf16* __restrict__ pre) {
    __shared__ __align__(16) __bf16 Bs[2048 * 8];   // 32 KB

    const int t    = threadIdx.x;
    const int lane = t & 63;
    const int w    = t >> 6;
    const int l15  = lane & 15;
    const int quad = lane >> 4;

    const int rbase = blockIdx.x * 64 + w * 16;
    int arow = rbase + l15;
    if (arow >= N_NODES) arow = N_NODES - 1;
    const float* aptr = x + (size_t)arow * D_IN + quad * 8;

    f32x4 acc[16];
#pragma unroll
    for (int i = 0; i < 16; ++i) acc[i] = (f32x4)0.f;

    for (int kb = 0; kb < 8; ++kb) {                  // BK = 64
        const __bf16* gsrc = wt2 + ((size_t)kb * 2048 + w * 64 + lane) * 8;
#pragma unroll
        for (int i = 0; i < 8; ++i) {
            __builtin_amdgcn_global_load_lds(
                (const __attribute__((address_space(1))) unsigned int*)(gsrc + (size_t)i * 2048),
                (__attribute__((address_space(3))) unsigned int*)(&Bs[(i * 256 + w * 64) * 8]),
                16, 0, 0);
        }
        bf16x8 afrag[2];
#pragma unroll
        for (int kk = 0; kk < 2; ++kk) {
            const float* ap = aptr + kb * 64 + kk * 32;
            float4 f0 = *(const float4*)(ap);
            float4 f1 = *(const float4*)(ap + 4);
            bf16x8 a;
            a[0] = (__bf16)f0.x; a[1] = (__bf16)f0.y;
            a[2] = (__bf16)f0.z; a[3] = (__bf16)f0.w;
            a[4] = (__bf16)f1.x; a[5] = (__bf16)f1.y;
            a[6] = (__bf16)f1.z; a[7] = (__bf16)f1.w;
            afrag[kk] = a;
        }
        __syncthreads();

#pragma unroll
        for (int kk = 0; kk < 2; ++kk) {
            const __bf16* bbase = &Bs[((kk * 4 + quad) * 256 + l15) * 8];
#pragma unroll
            for (int ct = 0; ct < 16; ++ct) {
                bf16x8 b = *(const bf16x8*)(bbase + ct * 128);
                acc[ct] = __builtin_amdgcn_mfma_f32_16x16x32_bf16(afrag[kk], b, acc[ct], 0, 0, 0);
            }
        }
        __syncthreads();
    }

#pragma unroll
    for (int ct = 0; ct < 16; ++ct) {
        const int col = ct * 16 + l15;
        const int s   = col >> 7;
        const int cp  = col & 127;
#pragma unroll
        for (int r = 0; r < 4; ++r) {
            const int row = rbase + quad * 4 + r;
            if (row < N_NODES)
                pre[((size_t)s * N_NODES + row) * D_OUT + cp] = (__bf16)acc[ct][r];
        }
    }
}

// ---------------------------------------------------------------------------
// Coarse scatter v2: full counting sort of the chunk IN LDS, then one linear
// coalesced sweep to global (bucket-contiguous runs, avg ~21 edges = 168 B).
// Payload: (val_bits, r<<16 | col)  -- both r and col fit in 16 bits.
// ---------------------------------------------------------------------------
__global__ __launch_bounds__(256) void scatter_coarse(const float* __restrict__ adj_vals,
                                                      const int* __restrict__ adj_rows,
                                                      const int* __restrict__ adj_cols,
                                                      int* __restrict__ gcursor,
                                                      uint2* __restrict__ coarse) {
    __shared__ int hist[NB_S];
    __shared__ int excl[NB_S];
    __shared__ int lbase[NB_S];
    __shared__ int rankc[NB_S];
    __shared__ int sc[256];
    __shared__ uint2 buf[CHUNK];                    // 32 KB, bucket-sorted chunk

    const int s = blockIdx.y;
    const int t = threadIdx.x;
    if (t < NB_S) { hist[t] = 0; rankc[t] = 0; }
    __syncthreads();

    const int e0 = blockIdx.x * CHUNK;
    int   rr[16]; int cc[16]; float vv[16];
#pragma unroll
    for (int i = 0; i < 16; ++i) {
        const int e = e0 + i * 256 + t;
        if (e < N_EDGES) {
            const size_t src = (size_t)s * N_EDGES + e;
            rr[i] = adj_rows[src];
            cc[i] = adj_cols[src];
            vv[i] = adj_vals[src];
            atomicAdd(&hist[rr[i] >> 8], 1);
        } else {
            rr[i] = -1; cc[i] = 0; vv[i] = 0.f;
        }
    }
    __syncthreads();

    // inclusive scan over the (padded) 196-bin histogram
    sc[t] = (t < NB_S) ? hist[t] : 0;
    __syncthreads();
    for (int off = 1; off < 256; off <<= 1) {
        const int a = (t >= off) ? sc[t - off] : 0;
        __syncthreads();
        sc[t] += a;
        __syncthreads();
    }
    if (t < NB_S) {
        excl[t]  = sc[t] - hist[t];
        lbase[t] = hist[t] ? atomicAdd(&gcursor[s * NB_S + t], hist[t]) : 0;
    }
    __syncthreads();

    // scatter into LDS (cheap scattered ds_writes)
#pragma unroll
    for (int i = 0; i < 16; ++i) {
        if (rr[i] >= 0) {
            const int b   = rr[i] >> 8;
            const int pos = excl[b] + atomicAdd(&rankc[b], 1);
            buf[pos] = make_uint2(__float_as_uint(vv[i]),
                                  ((unsigned)rr[i] << 16) | (unsigned)cc[i]);
        }
    }
    __syncthreads();

    // linear, coalesced global write
    const int total = min(e0 + CHUNK, N_EDGES) - e0;
    for (int i = t; i < total; i += 256) {
        const uint2 ed = buf[i];
        const int b   = ed.y >> 24;                 // r>>8
        const int dst = lbase[b] + (i - excl[b]);
        if (dst < CAP)                              // statistically impossible overflow guard
            coarse[(size_t)(s * NB_S + b) * CAP + dst] = ed;
    }
}

// ---------------------------------------------------------------------------
// Fine scatter v2: bucket -> registers (static unroll, no scratch), LDS
// 256-bin hist + scan, scatter into LDS row-sorted buffer, linear coalesced
// write to `sorted`. Emits per-row offsets/counts as before.
// ---------------------------------------------------------------------------
__global__ __launch_bounds__(256) void scatter_fine(const uint2* __restrict__ coarse,
                                                    const int* __restrict__ gcursor,
                                                    uint2* __restrict__ sorted,
                                                    int* __restrict__ row_off,
                                                    int* __restrict__ row_cnt) {
    __shared__ int rh[256];
    __shared__ int sd[256];
    __shared__ int rex[256];
    __shared__ int rc[256];
    __shared__ uint2 buf[CAP];                      // 36 KB, row-sorted bucket

    const int bk = blockIdx.x;      // 0..195
    const int s  = blockIdx.y;
    const int t  = threadIdx.x;
    const int bkt = s * NB_S + bk;
    const size_t b0 = (size_t)bkt * CAP;
    const int cnt = min(gcursor[bkt], CAP);

    rh[t] = 0; rc[t] = 0;
    __syncthreads();

    uint2 ev[18];                                   // 18*256 = 4608 = CAP
#pragma unroll
    for (int j = 0; j < 18; ++j) {
        const int i = j * 256 + t;
        if (i < cnt) {
            ev[j] = coarse[b0 + i];
            atomicAdd(&rh[(ev[j].y >> 16) & 255], 1);
        }
    }
    __syncthreads();

    const int myc = rh[t];
    sd[t] = myc;
    __syncthreads();
    for (int off = 1; off < 256; off <<= 1) {
        const int a = (t >= off) ? sd[t - off] : 0;
        __syncthreads();
        sd[t] += a;
        __syncthreads();
    }
    const int ex = sd[t] - myc;
    rex[t] = ex;
    const int row = (bk << 8) + t;
    if (row < N_NODES) {
        row_off[s * N_NODES + row] = (int)(b0 + ex);
        row_cnt[s * N_NODES + row] = myc;
    }
    __syncthreads();

    // scatter into LDS sorted-by-row
#pragma unroll
    for (int j = 0; j < 18; ++j) {
        const int i = j * 256 + t;
        if (i < cnt) {
            const int rl   = (ev[j].y >> 16) & 255;
            const int pos  = rex[rl] + atomicAdd(&rc[rl], 1);
            buf[pos] = make_uint2(ev[j].x, ev[j].y & 0xFFFFu);
        }
    }
    __syncthreads();

    // linear coalesced write
    for (int i = t; i < cnt; i += 256)
        sorted[b0 + i] = buf[i];
}

// ---------------------------------------------------------------------------
// Gather SpMM + bias + ReLU. (unchanged)
// ---------------------------------------------------------------------------
__global__ __launch_bounds__(256) void gather_spmm(const int* __restrict__ row_off,
                                                   const int* __restrict__ row_cnt,
                                                   const uint2* __restrict__ sorted,
                                                   const uint4* __restrict__ pre_q,  // 16 uint4 per row
                                                   const float* __restrict__ bias,
                                                   float* __restrict__ out) {
    const int lane = threadIdx.x & 63;
    const int q    = lane >> 4;            // quarter 0..3 -> edge j*4+q
    const int fl   = lane & 15;            // features fl*8 .. fl*8+7
    const int row  = blockIdx.x * 4 + (threadIdx.x >> 6);
    if (row >= N_NODES) return;

    float a[8];
#pragma unroll
    for (int k = 0; k < 8; ++k) a[k] = 0.f;

#pragma unroll
    for (int s = 0; s < N_SUP; ++s) {
        const int bin   = s * N_NODES + row;
        const int start = row_off[bin];
        const int cnt   = row_cnt[bin];
        const uint4* psup = pre_q + (size_t)s * N_NODES * 16 + fl;

        for (int e0 = 0; e0 < cnt; e0 += 64) {
            const int m = min(64, cnt - e0);
            int   c = 0;
            float v = 0.f;
            if (lane < m) {
                const uint2 ed = sorted[start + e0 + lane];
                v = __uint_as_float(ed.x);
                c = (int)ed.y;
            }
            const int steps = (m + 3) >> 2;

            auto step = [&](int jj) {
                const int   idx = (jj < m) ? jj : 0;
                float vj = __shfl(v, idx);
                const int cj = __shfl(c, idx);
                if (jj >= m) vj = 0.f;
                const uint4 p = psup[(size_t)cj * 16];
                a[0] += vj * __uint_as_float(p.x << 16);
                a[1] += vj * __uint_as_float(p.x & 0xffff0000u);
                a[2] += vj * __uint_as_float(p.y << 16);
                a[3] += vj * __uint_as_float(p.y & 0xffff0000u);
                a[4] += vj * __uint_as_float(p.z << 16);
                a[5] += vj * __uint_as_float(p.z & 0xffff0000u);
                a[6] += vj * __uint_as_float(p.w << 16);
                a[7] += vj * __uint_as_float(p.w & 0xffff0000u);
            };
            int jj = 0;
            for (; jj + 1 < steps; jj += 2) {
                step(jj * 4 + q);
                step(jj * 4 + 4 + q);
            }
            if (jj < steps) step(jj * 4 + q);
        }
    }

#pragma unroll
    for (int k = 0; k < 8; ++k) {
        a[k] += __shfl_xor(a[k], 16);
        a[k] += __shfl_xor(a[k], 32);
    }

    if (lane < 16) {
        const float4 b0 = *(const float4*)(bias + fl * 8);
        const float4 b1 = *(const float4*)(bias + fl * 8 + 4);
        float4 o0, o1;
        o0.x = fmaxf(a[0] + b0.x, 0.f);
        o0.y = fmaxf(a[1] + b0.y, 0.f);
        o0.z = fmaxf(a[2] + b0.z, 0.f);
        o0.w = fmaxf(a[3] + b0.w, 0.f);
        o1.x = fmaxf(a[4] + b1.x, 0.f);
        o1.y = fmaxf(a[5] + b1.y, 0.f);
        o1.z = fmaxf(a[6] + b1.z, 0.f);
        o1.w = fmaxf(a[7] + b1.w, 0.f);
        float* dst = out + (size_t)row * D_OUT + fl * 8;
        *(float4*)(dst)     = o0;
        *(float4*)(dst + 4) = o1;
    }
}

extern "C" void kernel_launch(void* const* d_in, const int* in_sizes, int n_in,
                              void* d_out, int out_size, void* d_ws, size_t ws_size,
                              hipStream_t stream) {
    const float* x        = (const float*)d_in[0];
    const float* kernels  = (const float*)d_in[1];
    const float* bias     = (const float*)d_in[2];
    const float* adj_vals = (const float*)d_in[3];
    const int*   adj_rows = (const int*)d_in[4];
    const int*   adj_cols = (const int*)d_in[5];
    float* out = (float*)d_out;

    // ---- workspace layout ----
    char* ws = (char*)d_ws;
    size_t off = 0;
    auto alloc = [&](size_t bytes) {
        char* p = ws + off;
        off += (bytes + 255) & ~(size_t)255;
        return p;
    };
    __bf16* pre    = (__bf16*)alloc(sizeof(__bf16) * N_SUP * N_NODES * D_OUT); // 25.6 MB
    __bf16* wt2    = (__bf16*)alloc(sizeof(__bf16) * D_IN * N_COLS);           // 256 KB
    uint2*  coarse = (uint2*) alloc(sizeof(uint2)  * NB * CAP);                // 14.5 MB
    uint2*  sorted = (uint2*) alloc(sizeof(uint2)  * NB * CAP);                // 14.5 MB
    int*    row_off = (int*)alloc(sizeof(int) * BINS);                         // 400 KB
    int*    row_cnt = (int*)alloc(sizeof(int) * BINS);                         // 400 KB
    int*    gcursor = (int*)alloc(sizeof(int) * NB);                           // 1.6 KB

    // ---- dense path (convert_w also zeroes gcursor) ----
    convert_w<<<(D_IN / 8) * N_COLS / 256, 256, 0, stream>>>(kernels, wt2, gcursor);
    gemm_bf16<<<(N_NODES + 63) / 64, 256, 0, stream>>>(x, wt2, pre);

    // ---- two-level counting sort, LDS-staged for coalesced global writes ----
    dim3 gc(NCHUNK, N_SUP);
    scatter_coarse<<<gc, 256, 0, stream>>>(adj_vals, adj_rows, adj_cols, gcursor, coarse);
    dim3 gf(NB_S, N_SUP);
    scatter_fine<<<gf, 256, 0, stream>>>(coarse, gcursor, sorted, row_off, row_cnt);

    // ---- gather SpMM + bias + ReLU ----
    gather_spmm<<<(N_NODES + 3) / 4, 256, 0, stream>>>(row_off, row_cnt, sorted,
                                                       (const uint4*)pre, bias, out);
}

// Round 2
// 270.968 us; speedup vs baseline: 1.0472x; 1.0205x over previous
//
#include <hip/hip_runtime.h>

#define N_NODES 50000
#define N_EDGES 800000
#define D_IN    512
#define D_OUT   128
#define N_SUP   2
#define N_COLS  (N_SUP * D_OUT)            // 256 combined output cols
#define BINS    (N_SUP * N_NODES)
#define NB_S    196                        // coarse buckets per support (256 rows each)
#define NB      (N_SUP * NB_S)             // 392 buckets
#define CAP     4608                       // fixed bucket capacity (mean 4082 + 8 sigma)
#define CHUNK   4096                       // edges per block in coarse pass
#define NCHUNK  ((N_EDGES + CHUNK - 1) / CHUNK)   // 196 chunks per support
#define GEMM_BLOCKS ((N_NODES + 63) / 64)         // 782
#define GHALF   391                               // gemm blocks per fused dispatch

typedef __attribute__((ext_vector_type(8))) __bf16 bf16x8;
typedef __attribute__((ext_vector_type(4))) float  f32x4;

// ---------------------------------------------------------------------------
// W convert: kernels [2][512][128] fp32 -> wt2 bf16 in GEMM staging order.
// Also zeroes gcursor.
// ---------------------------------------------------------------------------
__global__ __launch_bounds__(256) void convert_w(const float* __restrict__ w,
                                                 __bf16* __restrict__ wt2,
                                                 int* __restrict__ gcursor) {
    const int g = blockIdx.x * 256 + threadIdx.x;     // 16384 chunks
    if (g < NB) gcursor[g] = 0;
    if (g >= (D_IN / 8) * N_COLS) return;
    const int kq = g >> 8;
    const int n  = g & 255;
    const int s  = n >> 7;
    const int np = n & 127;
    bf16x8 v;
#pragma unroll
    for (int j = 0; j < 8; ++j) {
        const int k = kq * 8 + j;
        v[j] = (__bf16)w[((size_t)s * D_IN + k) * D_OUT + np];
    }
    *(bf16x8*)(wt2 + (size_t)g * 8) = v;
}

// ---------------------------------------------------------------------------
// GEMM body (one 64-row block): pre[s] = bf16(x) @ bf16(W[s]).  smem: 32 KB.
// ---------------------------------------------------------------------------
__device__ __forceinline__ void gemm_body(int rowblk, const float* __restrict__ x,
                                          const __bf16* __restrict__ wt2,
                                          __bf16* __restrict__ pre, char* smem) {
    __bf16* Bs = (__bf16*)smem;                       // 2048*8 bf16 = 32 KB

    const int t    = threadIdx.x;
    const int lane = t & 63;
    const int w    = t >> 6;
    const int l15  = lane & 15;
    const int quad = lane >> 4;

    const int rbase = rowblk * 64 + w * 16;
    int arow = rbase + l15;
    if (arow >= N_NODES) arow = N_NODES - 1;
    const float* aptr = x + (size_t)arow * D_IN + quad * 8;

    f32x4 acc[16];
#pragma unroll
    for (int i = 0; i < 16; ++i) acc[i] = (f32x4)0.f;

    for (int kb = 0; kb < 8; ++kb) {                  // BK = 64
        const __bf16* gsrc = wt2 + ((size_t)kb * 2048 + w * 64 + lane) * 8;
#pragma unroll
        for (int i = 0; i < 8; ++i) {
            __builtin_amdgcn_global_load_lds(
                (const __attribute__((address_space(1))) unsigned int*)(gsrc + (size_t)i * 2048),
                (__attribute__((address_space(3))) unsigned int*)(&Bs[(i * 256 + w * 64) * 8]),
                16, 0, 0);
        }
        bf16x8 afrag[2];
#pragma unroll
        for (int kk = 0; kk < 2; ++kk) {
            const float* ap = aptr + kb * 64 + kk * 32;
            float4 f0 = *(const float4*)(ap);
            float4 f1 = *(const float4*)(ap + 4);
            bf16x8 a;
            a[0] = (__bf16)f0.x; a[1] = (__bf16)f0.y;
            a[2] = (__bf16)f0.z; a[3] = (__bf16)f0.w;
            a[4] = (__bf16)f1.x; a[5] = (__bf16)f1.y;
            a[6] = (__bf16)f1.z; a[7] = (__bf16)f1.w;
            afrag[kk] = a;
        }
        __syncthreads();

#pragma unroll
        for (int kk = 0; kk < 2; ++kk) {
            const __bf16* bbase = &Bs[((kk * 4 + quad) * 256 + l15) * 8];
#pragma unroll
            for (int ct = 0; ct < 16; ++ct) {
                bf16x8 b = *(const bf16x8*)(bbase + ct * 128);
                acc[ct] = __builtin_amdgcn_mfma_f32_16x16x32_bf16(afrag[kk], b, acc[ct], 0, 0, 0);
            }
        }
        __syncthreads();
    }

#pragma unroll
    for (int ct = 0; ct < 16; ++ct) {
        const int col = ct * 16 + l15;
        const int s   = col >> 7;
        const int cp  = col & 127;
#pragma unroll
        for (int r = 0; r < 4; ++r) {
            const int row = rbase + quad * 4 + r;
            if (row < N_NODES)
                pre[((size_t)s * N_NODES + row) * D_OUT + cp] = (__bf16)acc[ct][r];
        }
    }
}

// ---------------------------------------------------------------------------
// Coarse scatter body (one 4096-edge chunk): counting sort in LDS, linear
// coalesced global write.  smem: 36928 B.
// Payload: (val_bits, r<<16 | col)
// ---------------------------------------------------------------------------
__device__ __forceinline__ void coarse_body(int cid,
                                            const float* __restrict__ adj_vals,
                                            const int* __restrict__ adj_rows,
                                            const int* __restrict__ adj_cols,
                                            int* __restrict__ gcursor,
                                            uint2* __restrict__ coarse, char* smem) {
    int*   hist  = (int*)smem;                  // 196
    int*   excl  = hist + NB_S;                 // 196
    int*   lbase = excl + NB_S;                 // 196
    int*   rankc = lbase + NB_S;                // 196
    int*   sc    = rankc + NB_S;                // 256   (total 4160 B, 16-aligned)
    uint2* buf   = (uint2*)(smem + 4160);       // 4096*8 = 32768 B

    const int s = cid / NCHUNK;
    const int t = threadIdx.x;
    if (t < NB_S) { hist[t] = 0; rankc[t] = 0; }
    __syncthreads();

    const int e0 = (cid % NCHUNK) * CHUNK;
    int   rr[16]; int cc[16]; float vv[16];
#pragma unroll
    for (int i = 0; i < 16; ++i) {
        const int e = e0 + i * 256 + t;
        if (e < N_EDGES) {
            const size_t src = (size_t)s * N_EDGES + e;
            rr[i] = adj_rows[src];
            cc[i] = adj_cols[src];
            vv[i] = adj_vals[src];
            atomicAdd(&hist[rr[i] >> 8], 1);
        } else {
            rr[i] = -1; cc[i] = 0; vv[i] = 0.f;
        }
    }
    __syncthreads();

    // inclusive scan over the (padded) 196-bin histogram
    sc[t] = (t < NB_S) ? hist[t] : 0;
    __syncthreads();
    for (int off = 1; off < 256; off <<= 1) {
        const int a = (t >= off) ? sc[t - off] : 0;
        __syncthreads();
        sc[t] += a;
        __syncthreads();
    }
    if (t < NB_S) {
        excl[t]  = sc[t] - hist[t];
        lbase[t] = hist[t] ? atomicAdd(&gcursor[s * NB_S + t], hist[t]) : 0;
    }
    __syncthreads();

    // scatter into LDS
#pragma unroll
    for (int i = 0; i < 16; ++i) {
        if (rr[i] >= 0) {
            const int b   = rr[i] >> 8;
            const int pos = excl[b] + atomicAdd(&rankc[b], 1);
            buf[pos] = make_uint2(__float_as_uint(vv[i]),
                                  ((unsigned)rr[i] << 16) | (unsigned)cc[i]);
        }
    }
    __syncthreads();

    // linear, coalesced global write
    const int total = min(e0 + CHUNK, N_EDGES) - e0;
    for (int i = t; i < total; i += 256) {
        const uint2 ed = buf[i];
        const int b   = ed.y >> 24;                 // r>>8
        const int dst = lbase[b] + (i - excl[b]);
        if (dst < CAP)                              // statistically impossible overflow guard
            coarse[(size_t)(s * NB_S + b) * CAP + dst] = ed;
    }
}

// ---------------------------------------------------------------------------
// Fine scatter body (one coarse bucket): hist+scan, LDS row-sort, linear
// coalesced write to sorted + per-row offsets/counts.  smem: 40960 B.
// ---------------------------------------------------------------------------
__device__ __forceinline__ void fine_body(int fid,
                                          const uint2* __restrict__ coarse,
                                          const int* __restrict__ gcursor,
                                          uint2* __restrict__ sorted,
                                          int* __restrict__ row_off,
                                          int* __restrict__ row_cnt, char* smem) {
    int*   rh  = (int*)smem;                    // 256
    int*   sd  = rh + 256;                      // 256
    int*   rex = sd + 256;                      // 256
    int*   rc  = rex + 256;                     // 256   (4096 B)
    uint2* buf = (uint2*)(smem + 4096);         // 4608*8 = 36864 B

    const int s  = fid / NB_S;
    const int bk = fid % NB_S;
    const int t  = threadIdx.x;
    const int bkt = s * NB_S + bk;
    const size_t b0 = (size_t)bkt * CAP;
    const int cnt = min(gcursor[bkt], CAP);

    rh[t] = 0; rc[t] = 0;
    __syncthreads();

    uint2 ev[18];                               // 18*256 = 4608 = CAP
#pragma unroll
    for (int j = 0; j < 18; ++j) {
        const int i = j * 256 + t;
        if (i < cnt) {
            ev[j] = coarse[b0 + i];
            atomicAdd(&rh[(ev[j].y >> 16) & 255], 1);
        }
    }
    __syncthreads();

    const int myc = rh[t];
    sd[t] = myc;
    __syncthreads();
    for (int off = 1; off < 256; off <<= 1) {
        const int a = (t >= off) ? sd[t - off] : 0;
        __syncthreads();
        sd[t] += a;
        __syncthreads();
    }
    const int ex = sd[t] - myc;
    rex[t] = ex;
    const int row = (bk << 8) + t;
    if (row < N_NODES) {
        row_off[s * N_NODES + row] = (int)(b0 + ex);
        row_cnt[s * N_NODES + row] = myc;
    }
    __syncthreads();

    // scatter into LDS sorted-by-row
#pragma unroll
    for (int j = 0; j < 18; ++j) {
        const int i = j * 256 + t;
        if (i < cnt) {
            const int rl   = (ev[j].y >> 16) & 255;
            const int pos  = rex[rl] + atomicAdd(&rc[rl], 1);
            buf[pos] = make_uint2(ev[j].x, ev[j].y & 0xFFFFu);
        }
    }
    __syncthreads();

    // linear coalesced write
    for (int i = t; i < cnt; i += 256)
        sorted[b0 + i] = buf[i];
}

// ---------------------------------------------------------------------------
// Fused dispatch A: gemm rows [0, 391*64) ‖ scatter_coarse (independent).
// ---------------------------------------------------------------------------
__global__ __launch_bounds__(256) void fused_gemm_coarse(const float* __restrict__ x,
                                                         const __bf16* __restrict__ wt2,
                                                         __bf16* __restrict__ pre,
                                                         const float* __restrict__ adj_vals,
                                                         const int* __restrict__ adj_rows,
                                                         const int* __restrict__ adj_cols,
                                                         int* __restrict__ gcursor,
                                                         uint2* __restrict__ coarse) {
    __shared__ __align__(16) char smem[36928];
    const int bid = blockIdx.x;
    if (bid < GHALF)
        gemm_body(bid, x, wt2, pre, smem);
    else
        coarse_body(bid - GHALF, adj_vals, adj_rows, adj_cols, gcursor, coarse, smem);
}

// ---------------------------------------------------------------------------
// Fused dispatch B: gemm rows [391*64, N) ‖ scatter_fine (needs coarse only).
// ---------------------------------------------------------------------------
__global__ __launch_bounds__(256) void fused_gemm_fine(const float* __restrict__ x,
                                                       const __bf16* __restrict__ wt2,
                                                       __bf16* __restrict__ pre,
                                                       const uint2* __restrict__ coarse,
                                                       const int* __restrict__ gcursor,
                                                       uint2* __restrict__ sorted,
                                                       int* __restrict__ row_off,
                                                       int* __restrict__ row_cnt) {
    __shared__ __align__(16) char smem[40960];
    const int bid = blockIdx.x;
    if (bid < GEMM_BLOCKS - GHALF)
        gemm_body(GHALF + bid, x, wt2, pre, smem);
    else
        fine_body(bid - (GEMM_BLOCKS - GHALF), coarse, gcursor, sorted, row_off, row_cnt, smem);
}

// ---------------------------------------------------------------------------
// Gather SpMM + bias + ReLU. (unchanged)
// ---------------------------------------------------------------------------
__global__ __launch_bounds__(256) void gather_spmm(const int* __restrict__ row_off,
                                                   const int* __restrict__ row_cnt,
                                                   const uint2* __restrict__ sorted,
                                                   const uint4* __restrict__ pre_q,  // 16 uint4 per row
                                                   const float* __restrict__ bias,
                                                   float* __restrict__ out) {
    const int lane = threadIdx.x & 63;
    const int q    = lane >> 4;            // quarter 0..3 -> edge j*4+q
    const int fl   = lane & 15;            // features fl*8 .. fl*8+7
    const int row  = blockIdx.x * 4 + (threadIdx.x >> 6);
    if (row >= N_NODES) return;

    float a[8];
#pragma unroll
    for (int k = 0; k < 8; ++k) a[k] = 0.f;

#pragma unroll
    for (int s = 0; s < N_SUP; ++s) {
        const int bin   = s * N_NODES + row;
        const int start = row_off[bin];
        const int cnt   = row_cnt[bin];
        const uint4* psup = pre_q + (size_t)s * N_NODES * 16 + fl;

        for (int e0 = 0; e0 < cnt; e0 += 64) {
            const int m = min(64, cnt - e0);
            int   c = 0;
            float v = 0.f;
            if (lane < m) {
                const uint2 ed = sorted[start + e0 + lane];
                v = __uint_as_float(ed.x);
                c = (int)ed.y;
            }
            const int steps = (m + 3) >> 2;

            auto step = [&](int jj) {
                const int   idx = (jj < m) ? jj : 0;
                float vj = __shfl(v, idx);
                const int cj = __shfl(c, idx);
                if (jj >= m) vj = 0.f;
                const uint4 p = psup[(size_t)cj * 16];
                a[0] += vj * __uint_as_float(p.x << 16);
                a[1] += vj * __uint_as_float(p.x & 0xffff0000u);
                a[2] += vj * __uint_as_float(p.y << 16);
                a[3] += vj * __uint_as_float(p.y & 0xffff0000u);
                a[4] += vj * __uint_as_float(p.z << 16);
                a[5] += vj * __uint_as_float(p.z & 0xffff0000u);
                a[6] += vj * __uint_as_float(p.w << 16);
                a[7] += vj * __uint_as_float(p.w & 0xffff0000u);
            };
            int jj = 0;
            for (; jj + 1 < steps; jj += 2) {
                step(jj * 4 + q);
                step(jj * 4 + 4 + q);
            }
            if (jj < steps) step(jj * 4 + q);
        }
    }

#pragma unroll
    for (int k = 0; k < 8; ++k) {
        a[k] += __shfl_xor(a[k], 16);
        a[k] += __shfl_xor(a[k], 32);
    }

    if (lane < 16) {
        const float4 b0 = *(const float4*)(bias + fl * 8);
        const float4 b1 = *(const float4*)(bias + fl * 8 + 4);
        float4 o0, o1;
        o0.x = fmaxf(a[0] + b0.x, 0.f);
        o0.y = fmaxf(a[1] + b0.y, 0.f);
        o0.z = fmaxf(a[2] + b0.z, 0.f);
        o0.w = fmaxf(a[3] + b0.w, 0.f);
        o1.x = fmaxf(a[4] + b1.x, 0.f);
        o1.y = fmaxf(a[5] + b1.y, 0.f);
        o1.z = fmaxf(a[6] + b1.z, 0.f);
        o1.w = fmaxf(a[7] + b1.w, 0.f);
        float* dst = out + (size_t)row * D_OUT + fl * 8;
        *(float4*)(dst)     = o0;
        *(float4*)(dst + 4) = o1;
    }
}

extern "C" void kernel_launch(void* const* d_in, const int* in_sizes, int n_in,
                              void* d_out, int out_size, void* d_ws, size_t ws_size,
                              hipStream_t stream) {
    const float* x        = (const float*)d_in[0];
    const float* kernels  = (const float*)d_in[1];
    const float* bias     = (const float*)d_in[2];
    const float* adj_vals = (const float*)d_in[3];
    const int*   adj_rows = (const int*)d_in[4];
    const int*   adj_cols = (const int*)d_in[5];
    float* out = (float*)d_out;

    // ---- workspace layout ----
    char* ws = (char*)d_ws;
    size_t off = 0;
    auto alloc = [&](size_t bytes) {
        char* p = ws + off;
        off += (bytes + 255) & ~(size_t)255;
        return p;
    };
    __bf16* pre    = (__bf16*)alloc(sizeof(__bf16) * N_SUP * N_NODES * D_OUT); // 25.6 MB
    __bf16* wt2    = (__bf16*)alloc(sizeof(__bf16) * D_IN * N_COLS);           // 256 KB
    uint2*  coarse = (uint2*) alloc(sizeof(uint2)  * NB * CAP);                // 14.5 MB
    uint2*  sorted = (uint2*) alloc(sizeof(uint2)  * NB * CAP);                // 14.5 MB
    int*    row_off = (int*)alloc(sizeof(int) * BINS);                         // 400 KB
    int*    row_cnt = (int*)alloc(sizeof(int) * BINS);                         // 400 KB
    int*    gcursor = (int*)alloc(sizeof(int) * NB);                           // 1.6 KB

    // K1: W convert + gcursor zero
    convert_w<<<(D_IN / 8) * N_COLS / 256, 256, 0, stream>>>(kernels, wt2, gcursor);

    // K2: gemm rows [0, 25024) ‖ scatter_coarse
    fused_gemm_coarse<<<GHALF + NB, 256, 0, stream>>>(x, wt2, pre,
                                                      adj_vals, adj_rows, adj_cols,
                                                      gcursor, coarse);

    // K3: gemm rows [25024, 50000) ‖ scatter_fine
    fused_gemm_fine<<<(GEMM_BLOCKS - GHALF) + NB, 256, 0, stream>>>(x, wt2, pre,
                                                                    coarse, gcursor, sorted,
                                                                    row_off, row_cnt);

    // K4: gather SpMM + bias + ReLU
    gather_spmm<<<(N_NODES + 3) / 4, 256, 0, stream>>>(row_off, row_cnt, sorted,
                                                       (const uint4*)pre, bias, out);
}

// Round 3
// 266.019 us; speedup vs baseline: 1.0667x; 1.0186x over previous
//
#include <hip/hip_runtime.h>

#define N_NODES 50000
#define N_EDGES 800000
#define D_IN    512
#define D_OUT   128
#define N_SUP   2
#define N_COLS  (N_SUP * D_OUT)            // 256 combined output cols
#define BINS    (N_SUP * N_NODES)
#define NB_S    196                        // coarse buckets per support (256 rows each)
#define NB      (N_SUP * NB_S)             // 392 buckets
#define CAP     4608                       // fixed bucket capacity (mean 4082 + 8 sigma)
#define CHUNK   4096                       // edges per block in coarse pass
#define NCHUNK  ((N_EDGES + CHUNK - 1) / CHUNK)   // 196 chunks per support

#define TILE_R  16
#define NTILES  (N_NODES / TILE_R)         // 3125 exactly
#define GGRID   256                        // persistent gemm blocks

typedef __attribute__((ext_vector_type(8))) __bf16 bf16x8;
typedef __attribute__((ext_vector_type(4))) float  f32x4;

// ---------------------------------------------------------------------------
// W convert: kernels [2][512][128] fp32 -> wt2 bf16, chunk g = (k>>3)*256+col,
// 8 K-contiguous bf16 per chunk (MFMA B-frag order). Also zeroes gcursor.
// ---------------------------------------------------------------------------
__global__ __launch_bounds__(256) void convert_w(const float* __restrict__ w,
                                                 __bf16* __restrict__ wt2,
                                                 int* __restrict__ gcursor) {
    const int g = blockIdx.x * 256 + threadIdx.x;     // 16384 chunks
    if (g < NB) gcursor[g] = 0;
    if (g >= (D_IN / 8) * N_COLS) return;
    const int kq = g >> 8;
    const int n  = g & 255;
    const int s  = n >> 7;
    const int np = n & 127;
    bf16x8 v;
#pragma unroll
    for (int j = 0; j < 8; ++j) {
        const int k = kq * 8 + j;
        v[j] = (__bf16)w[((size_t)s * D_IN + k) * D_OUT + np];
    }
    *(bf16x8*)(wt2 + (size_t)g * 8) = v;
}

// ---------------------------------------------------------------------------
// GEMM v3: B held ENTIRELY in registers (128 VGPR/wave = 32 cols x K=512).
// 8 waves/block cover all 256 cols. A streamed through a 16 KB swizzled LDS
// tile (16 rows), 2 barriers per TILE (not per K-step). 256 persistent
// blocks grid-stride over 3125 tiles.
// ---------------------------------------------------------------------------
__global__ __launch_bounds__(512, 2) void gemm_bf16_v2(const float* __restrict__ x,
                                                       const __bf16* __restrict__ wt2,
                                                       __bf16* __restrict__ pre) {
    __shared__ __align__(16) __bf16 As[TILE_R * 64 * 8];   // 16 KB: 16 rows x 64 chunks

    const int t    = threadIdx.x;
    const int lane = t & 63;
    const int w    = t >> 6;            // wave 0..7 -> cols [w*32, w*32+32)
    const int l15  = lane & 15;
    const int quad = lane >> 4;

    // ---- B -> registers: frag(ct,kb): chunk (kb*4+quad)*256 + w*32 + ct*16 + l15
    bf16x8 B0[16], B1[16];
#pragma unroll
    for (int kb = 0; kb < 16; ++kb) {
        const size_t g0 = (size_t)(kb * 4 + quad) * 256 + w * 32 + l15;
        B0[kb] = *(const bf16x8*)(wt2 + g0 * 8);
        B1[kb] = *(const bf16x8*)(wt2 + (g0 + 16) * 8);
    }

    // output column bookkeeping (support / in-support col are wave-static)
    const int s_out = w >> 2;
    const int cp0   = (w & 3) * 32 + l15;

    // staging role: thread -> (row srow, 2 chunks at sc0)
    const int srow = t >> 5;            // 0..15
    const int sc0  = (t & 31) * 2;      // chunk pair (chunk = 8 floats = 16 B bf16)
    const int swz  = srow & 7;

    int tile = blockIdx.x;
    float4 f0, f1, f2, f3;
    {   // preload tile 0
        const float* src = x + ((size_t)tile * TILE_R + srow) * D_IN + sc0 * 8;
        f0 = ((const float4*)src)[0];
        f1 = ((const float4*)src)[1];
        f2 = ((const float4*)src)[2];
        f3 = ((const float4*)src)[3];
    }

    while (tile < NTILES) {
        // convert the in-flight tile to bf16
        bf16x8 lo, hi;
        lo[0] = (__bf16)f0.x; lo[1] = (__bf16)f0.y; lo[2] = (__bf16)f0.z; lo[3] = (__bf16)f0.w;
        lo[4] = (__bf16)f1.x; lo[5] = (__bf16)f1.y; lo[6] = (__bf16)f1.z; lo[7] = (__bf16)f1.w;
        hi[0] = (__bf16)f2.x; hi[1] = (__bf16)f2.y; hi[2] = (__bf16)f2.z; hi[3] = (__bf16)f2.w;
        hi[4] = (__bf16)f3.x; hi[5] = (__bf16)f3.y; hi[6] = (__bf16)f3.z; hi[7] = (__bf16)f3.w;

        __syncthreads();     // previous tile's compute done -> LDS free
        *(bf16x8*)&As[((size_t)srow * 64 + (sc0       ^ swz)) * 8] = lo;
        *(bf16x8*)&As[((size_t)srow * 64 + ((sc0 + 1) ^ swz)) * 8] = hi;
        __syncthreads();     // tile staged

        // prefetch next tile while computing this one
        const int next = tile + GGRID;
        if (next < NTILES) {
            const float* src = x + ((size_t)next * TILE_R + srow) * D_IN + sc0 * 8;
            f0 = ((const float4*)src)[0];
            f1 = ((const float4*)src)[1];
            f2 = ((const float4*)src)[2];
            f3 = ((const float4*)src)[3];
        }

        // compute: 16 rows x 32 cols, full K
        f32x4 acc0 = (f32x4)0.f, acc1 = (f32x4)0.f;
#pragma unroll
        for (int kb = 0; kb < 16; ++kb) {
            const int c = (kb * 4 + quad) ^ (l15 & 7);
            bf16x8 a = *(const bf16x8*)&As[((size_t)l15 * 64 + c) * 8];
            acc0 = __builtin_amdgcn_mfma_f32_16x16x32_bf16(a, B0[kb], acc0, 0, 0, 0);
            acc1 = __builtin_amdgcn_mfma_f32_16x16x32_bf16(a, B1[kb], acc1, 0, 0, 0);
        }

        // epilogue: C layout col=lane&15, row=quad*4+r
        __bf16* dst = pre + ((size_t)s_out * N_NODES + (size_t)tile * TILE_R + quad * 4) * D_OUT + cp0;
#pragma unroll
        for (int r = 0; r < 4; ++r) {
            dst[(size_t)r * D_OUT]      = (__bf16)acc0[r];
            dst[(size_t)r * D_OUT + 16] = (__bf16)acc1[r];
        }

        tile = next;
    }
}

// ---------------------------------------------------------------------------
// Coarse scatter: counting sort of a 4096-edge chunk in LDS, then linear
// coalesced global write. Payload: (val_bits, r<<16 | col).
// ---------------------------------------------------------------------------
__global__ __launch_bounds__(256) void scatter_coarse(const float* __restrict__ adj_vals,
                                                      const int* __restrict__ adj_rows,
                                                      const int* __restrict__ adj_cols,
                                                      int* __restrict__ gcursor,
                                                      uint2* __restrict__ coarse) {
    __shared__ int hist[NB_S];
    __shared__ int excl[NB_S];
    __shared__ int lbase[NB_S];
    __shared__ int rankc[NB_S];
    __shared__ int sc[256];
    __shared__ uint2 buf[CHUNK];                    // 32 KB, bucket-sorted chunk

    const int s = blockIdx.y;
    const int t = threadIdx.x;
    if (t < NB_S) { hist[t] = 0; rankc[t] = 0; }
    __syncthreads();

    const int e0 = blockIdx.x * CHUNK;
    int   rr[16]; int cc[16]; float vv[16];
#pragma unroll
    for (int i = 0; i < 16; ++i) {
        const int e = e0 + i * 256 + t;
        if (e < N_EDGES) {
            const size_t src = (size_t)s * N_EDGES + e;
            rr[i] = adj_rows[src];
            cc[i] = adj_cols[src];
            vv[i] = adj_vals[src];
            atomicAdd(&hist[rr[i] >> 8], 1);
        } else {
            rr[i] = -1; cc[i] = 0; vv[i] = 0.f;
        }
    }
    __syncthreads();

    sc[t] = (t < NB_S) ? hist[t] : 0;
    __syncthreads();
    for (int off = 1; off < 256; off <<= 1) {
        const int a = (t >= off) ? sc[t - off] : 0;
        __syncthreads();
        sc[t] += a;
        __syncthreads();
    }
    if (t < NB_S) {
        excl[t]  = sc[t] - hist[t];
        lbase[t] = hist[t] ? atomicAdd(&gcursor[s * NB_S + t], hist[t]) : 0;
    }
    __syncthreads();

#pragma unroll
    for (int i = 0; i < 16; ++i) {
        if (rr[i] >= 0) {
            const int b   = rr[i] >> 8;
            const int pos = excl[b] + atomicAdd(&rankc[b], 1);
            buf[pos] = make_uint2(__float_as_uint(vv[i]),
                                  ((unsigned)rr[i] << 16) | (unsigned)cc[i]);
        }
    }
    __syncthreads();

    const int total = min(e0 + CHUNK, N_EDGES) - e0;
    for (int i = t; i < total; i += 256) {
        const uint2 ed = buf[i];
        const int b   = ed.y >> 24;                 // r>>8
        const int dst = lbase[b] + (i - excl[b]);
        if (dst < CAP)
            coarse[(size_t)(s * NB_S + b) * CAP + dst] = ed;
    }
}

// ---------------------------------------------------------------------------
// Fine scatter: bucket -> regs, 256-bin hist+scan, LDS row-sort, linear
// coalesced write to `sorted` + per-row offsets/counts.
// ---------------------------------------------------------------------------
__global__ __launch_bounds__(256) void scatter_fine(const uint2* __restrict__ coarse,
                                                    const int* __restrict__ gcursor,
                                                    uint2* __restrict__ sorted,
                                                    int* __restrict__ row_off,
                                                    int* __restrict__ row_cnt) {
    __shared__ int rh[256];
    __shared__ int sd[256];
    __shared__ int rex[256];
    __shared__ int rc[256];
    __shared__ uint2 buf[CAP];                      // 36 KB, row-sorted bucket

    const int bk = blockIdx.x;      // 0..195
    const int s  = blockIdx.y;
    const int t  = threadIdx.x;
    const int bkt = s * NB_S + bk;
    const size_t b0 = (size_t)bkt * CAP;
    const int cnt = min(gcursor[bkt], CAP);

    rh[t] = 0; rc[t] = 0;
    __syncthreads();

    uint2 ev[18];                                   // 18*256 = 4608 = CAP
#pragma unroll
    for (int j = 0; j < 18; ++j) {
        const int i = j * 256 + t;
        if (i < cnt) {
            ev[j] = coarse[b0 + i];
            atomicAdd(&rh[(ev[j].y >> 16) & 255], 1);
        }
    }
    __syncthreads();

    const int myc = rh[t];
    sd[t] = myc;
    __syncthreads();
    for (int off = 1; off < 256; off <<= 1) {
        const int a = (t >= off) ? sd[t - off] : 0;
        __syncthreads();
        sd[t] += a;
        __syncthreads();
    }
    const int ex = sd[t] - myc;
    rex[t] = ex;
    const int row = (bk << 8) + t;
    if (row < N_NODES) {
        row_off[s * N_NODES + row] = (int)(b0 + ex);
        row_cnt[s * N_NODES + row] = myc;
    }
    __syncthreads();

#pragma unroll
    for (int j = 0; j < 18; ++j) {
        const int i = j * 256 + t;
        if (i < cnt) {
            const int rl   = (ev[j].y >> 16) & 255;
            const int pos  = rex[rl] + atomicAdd(&rc[rl], 1);
            buf[pos] = make_uint2(ev[j].x, ev[j].y & 0xFFFFu);
        }
    }
    __syncthreads();

    for (int i = t; i < cnt; i += 256)
        sorted[b0 + i] = buf[i];
}

// ---------------------------------------------------------------------------
// Gather SpMM + bias + ReLU. (unchanged)
// ---------------------------------------------------------------------------
__global__ __launch_bounds__(256) void gather_spmm(const int* __restrict__ row_off,
                                                   const int* __restrict__ row_cnt,
                                                   const uint2* __restrict__ sorted,
                                                   const uint4* __restrict__ pre_q,  // 16 uint4 per row
                                                   const float* __restrict__ bias,
                                                   float* __restrict__ out) {
    const int lane = threadIdx.x & 63;
    const int q    = lane >> 4;            // quarter 0..3 -> edge j*4+q
    const int fl   = lane & 15;            // features fl*8 .. fl*8+7
    const int row  = blockIdx.x * 4 + (threadIdx.x >> 6);
    if (row >= N_NODES) return;

    float a[8];
#pragma unroll
    for (int k = 0; k < 8; ++k) a[k] = 0.f;

#pragma unroll
    for (int s = 0; s < N_SUP; ++s) {
        const int bin   = s * N_NODES + row;
        const int start = row_off[bin];
        const int cnt   = row_cnt[bin];
        const uint4* psup = pre_q + (size_t)s * N_NODES * 16 + fl;

        for (int e0 = 0; e0 < cnt; e0 += 64) {
            const int m = min(64, cnt - e0);
            int   c = 0;
            float v = 0.f;
            if (lane < m) {
                const uint2 ed = sorted[start + e0 + lane];
                v = __uint_as_float(ed.x);
                c = (int)ed.y;
            }
            const int steps = (m + 3) >> 2;

            auto step = [&](int jj) {
                const int   idx = (jj < m) ? jj : 0;
                float vj = __shfl(v, idx);
                const int cj = __shfl(c, idx);
                if (jj >= m) vj = 0.f;
                const uint4 p = psup[(size_t)cj * 16];
                a[0] += vj * __uint_as_float(p.x << 16);
                a[1] += vj * __uint_as_float(p.x & 0xffff0000u);
                a[2] += vj * __uint_as_float(p.y << 16);
                a[3] += vj * __uint_as_float(p.y & 0xffff0000u);
                a[4] += vj * __uint_as_float(p.z << 16);
                a[5] += vj * __uint_as_float(p.z & 0xffff0000u);
                a[6] += vj * __uint_as_float(p.w << 16);
                a[7] += vj * __uint_as_float(p.w & 0xffff0000u);
            };
            int jj = 0;
            for (; jj + 1 < steps; jj += 2) {
                step(jj * 4 + q);
                step(jj * 4 + 4 + q);
            }
            if (jj < steps) step(jj * 4 + q);
        }
    }

#pragma unroll
    for (int k = 0; k < 8; ++k) {
        a[k] += __shfl_xor(a[k], 16);
        a[k] += __shfl_xor(a[k], 32);
    }

    if (lane < 16) {
        const float4 b0 = *(const float4*)(bias + fl * 8);
        const float4 b1 = *(const float4*)(bias + fl * 8 + 4);
        float4 o0, o1;
        o0.x = fmaxf(a[0] + b0.x, 0.f);
        o0.y = fmaxf(a[1] + b0.y, 0.f);
        o0.z = fmaxf(a[2] + b0.z, 0.f);
        o0.w = fmaxf(a[3] + b0.w, 0.f);
        o1.x = fmaxf(a[4] + b1.x, 0.f);
        o1.y = fmaxf(a[5] + b1.y, 0.f);
        o1.z = fmaxf(a[6] + b1.z, 0.f);
        o1.w = fmaxf(a[7] + b1.w, 0.f);
        float* dst = out + (size_t)row * D_OUT + fl * 8;
        *(float4*)(dst)     = o0;
        *(float4*)(dst + 4) = o1;
    }
}

extern "C" void kernel_launch(void* const* d_in, const int* in_sizes, int n_in,
                              void* d_out, int out_size, void* d_ws, size_t ws_size,
                              hipStream_t stream) {
    const float* x        = (const float*)d_in[0];
    const float* kernels  = (const float*)d_in[1];
    const float* bias     = (const float*)d_in[2];
    const float* adj_vals = (const float*)d_in[3];
    const int*   adj_rows = (const int*)d_in[4];
    const int*   adj_cols = (const int*)d_in[5];
    float* out = (float*)d_out;

    // ---- workspace layout ----
    char* ws = (char*)d_ws;
    size_t off = 0;
    auto alloc = [&](size_t bytes) {
        char* p = ws + off;
        off += (bytes + 255) & ~(size_t)255;
        return p;
    };
    __bf16* pre    = (__bf16*)alloc(sizeof(__bf16) * N_SUP * N_NODES * D_OUT); // 25.6 MB
    __bf16* wt2    = (__bf16*)alloc(sizeof(__bf16) * D_IN * N_COLS);           // 256 KB
    uint2*  coarse = (uint2*) alloc(sizeof(uint2)  * NB * CAP);                // 14.5 MB
    uint2*  sorted = (uint2*) alloc(sizeof(uint2)  * NB * CAP);                // 14.5 MB
    int*    row_off = (int*)alloc(sizeof(int) * BINS);                         // 400 KB
    int*    row_cnt = (int*)alloc(sizeof(int) * BINS);                         // 400 KB
    int*    gcursor = (int*)alloc(sizeof(int) * NB);                           // 1.6 KB

    // K1: W convert + gcursor zero
    convert_w<<<(D_IN / 8) * N_COLS / 256, 256, 0, stream>>>(kernels, wt2, gcursor);

    // K2: B-in-register streaming GEMM
    gemm_bf16_v2<<<GGRID, 512, 0, stream>>>(x, wt2, pre);

    // K3/K4: two-level counting sort
    dim3 gc(NCHUNK, N_SUP);
    scatter_coarse<<<gc, 256, 0, stream>>>(adj_vals, adj_rows, adj_cols, gcursor, coarse);
    dim3 gf(NB_S, N_SUP);
    scatter_fine<<<gf, 256, 0, stream>>>(coarse, gcursor, sorted, row_off, row_cnt);

    // K5: gather SpMM + bias + ReLU
    gather_spmm<<<(N_NODES + 3) / 4, 256, 0, stream>>>(row_off, row_cnt, sorted,
                                                       (const uint4*)pre, bias, out);
}